// Round 8
// baseline (303.280 us; speedup 1.0000x reference)
//
#include <hip/hip_runtime.h>

// ---------------------------------------------------------------------------
// TransformerBlock on MI355X (gfx950): bf16 MFMA pipeline
//   B=4 S=2048 D=768 H=12 hs=64 F=3072, M=B*S=8192
// Round 8: gemm256 v3 — fixed MFMA ordering (k-half outer, dep distance 8)
//          + re-derived vmcnt ledger (quadrant-band A staging, 3-phase-min
//          wait windows: w8@Ph2, w6@Ph4, w8@Ph6, w6@Ph8). Attn QK^T MFMA
//          dependency break. Layout/launches otherwise as R7.
// ---------------------------------------------------------------------------

typedef __attribute__((ext_vector_type(4))) float f32x4;
typedef __attribute__((ext_vector_type(8))) short bf16x8;   // 8 bf16 in 4 VGPRs
typedef __attribute__((ext_vector_type(4))) unsigned short u16x4;

#define GLB_AS __attribute__((address_space(1)))
#define LDS_AS __attribute__((address_space(3)))

__device__ __forceinline__ unsigned short f2bf(float f) {
  unsigned int u = __float_as_uint(f);
  u = (u + 0x7FFFu + ((u >> 16) & 1u)) >> 16;   // RNE
  return (unsigned short)u;
}

__device__ __forceinline__ void gload16(const void* g, void* l) {
  __builtin_amdgcn_global_load_lds((const GLB_AS unsigned int*)g,
                                   (LDS_AS unsigned int*)l, 16, 0, 0);
}

// bijective XCD swizzle (m204): contiguous chunk of wg-ids per XCD
__device__ __forceinline__ int xcd_swz(int orig, int nwg) {
  int q = nwg >> 3, r = nwg & 7;
  int xcd = orig & 7, rest = orig >> 3;
  return (xcd < r ? xcd * (q + 1) : r * (q + 1) + (xcd - r) * q) + rest;
}

// ---------------------------------------------------------------- cast x ---
__global__ void castx(const float* __restrict__ in, unsigned short* __restrict__ out, int n) {
  int i = (blockIdx.x * 256 + threadIdx.x) * 4;
  if (i < n) {
    float4 f = *(const float4*)&in[i];
    u16x4 o;
    o[0] = f2bf(f.x); o[1] = f2bf(f.y); o[2] = f2bf(f.z); o[3] = f2bf(f.w);
    *(u16x4*)&out[i] = o;
  }
}

// --------------------------------------------------- split-K reduce (W2) ---
__global__ void reduce2(const float* __restrict__ p, float* __restrict__ out, int n) {
  int i = (blockIdx.x * 256 + threadIdx.x) * 4;
  if (i < n) {
    f32x4 a = *(const f32x4*)&p[i];
    f32x4 b = *(const f32x4*)&p[n + i];
    a += b;
    *(f32x4*)&out[i] = a;
  }
}

// ---------------------------------------------- weight transpose + cast ----
__global__ void tcast(const float* __restrict__ in, unsigned short* __restrict__ out,
                      int R, int C, float scale) {
  __shared__ float tile[32][33];
  const float* inb = in + (size_t)blockIdx.z * R * C;
  unsigned short* outb = out + (size_t)blockIdx.z * R * C;
  int bx = blockIdx.x * 32;  // C dim
  int by = blockIdx.y * 32;  // R dim
  int tx = threadIdx.x, ty = threadIdx.y;
  #pragma unroll
  for (int i = 0; i < 32; i += 8)
    tile[ty + i][tx] = inb[(size_t)(by + ty + i) * C + bx + tx];
  __syncthreads();
  #pragma unroll
  for (int i = 0; i < 32; i += 8)
    outb[(size_t)(bx + ty + i) * R + by + tx] = f2bf(tile[tx][ty + i] * scale);
}

// Wq/Wk/Wv transposes in one launch: z in [0,36), wsel=z/12 picks the matrix.
__global__ void tcast3(const float* __restrict__ Wq, const float* __restrict__ Wk,
                       const float* __restrict__ Wv, unsigned short* __restrict__ out,
                       float qscale) {
  __shared__ float tile[32][33];
  const int R = 768, C = 64;
  int z = blockIdx.z, wsel = z / 12, head = z % 12;
  const float* in = (wsel == 0 ? Wq : wsel == 1 ? Wk : Wv) + (size_t)head * R * C;
  unsigned short* outb = out + (size_t)wsel * R * R + (size_t)head * R * C;
  float scale = wsel == 0 ? qscale : 1.0f;
  int bx = blockIdx.x * 32;  // C dim
  int by = blockIdx.y * 32;  // R dim
  int tx = threadIdx.x, ty = threadIdx.y;
  #pragma unroll
  for (int i = 0; i < 32; i += 8)
    tile[ty + i][tx] = in[(size_t)(by + ty + i) * C + bx + tx];
  __syncthreads();
  #pragma unroll
  for (int i = 0; i < 32; i += 8)
    outb[(size_t)(bx + ty + i) * R + by + tx] = f2bf(tile[tx][ty + i] * scale);
}

// ------------------------------------------------- v -> vT (bf16->bf16) ----
__global__ void vtrans(const unsigned short* __restrict__ v, unsigned short* __restrict__ vT) {
  __shared__ unsigned short tile[32][33];
  int bh = blockIdx.z, b = bh / 12, h = bh % 12;
  int s0 = blockIdx.x * 32, e0 = blockIdx.y * 32;
  int tx = threadIdx.x, ty = threadIdx.y;
  #pragma unroll
  for (int i = 0; i < 32; i += 8)
    tile[ty + i][tx] = v[(size_t)(b * 2048 + s0 + ty + i) * 768 + h * 64 + e0 + tx];
  __syncthreads();
  #pragma unroll
  for (int i = 0; i < 32; i += 8)
    vT[(size_t)((b * 12 + h) * 64 + e0 + ty + i) * 2048 + s0 + tx] = tile[tx][ty + i];
}

// --------------------------------------------------------- GEMM 128x128 ---
// (Wo: narrow N, small K)
template <int EPI>
__global__ void gemm_bf16(const unsigned short* __restrict__ A,
                          const unsigned short* __restrict__ Bt,
                          const float* __restrict__ bias,
                          const float* __restrict__ resid,
                          float* __restrict__ Cf,
                          unsigned short* __restrict__ Cb,
                          int M, int N, int K, int gy, size_t segN) {
  __shared__ unsigned short Alds[2][128 * 32];
  __shared__ unsigned short Blds[2][128 * 32];
  const int tid = threadIdx.x;
  const int lane = tid & 63;
  const int w = tid >> 6;
  const int wm = w & 1, wn = w >> 1;
  const int wg = xcd_swz(blockIdx.x, gridDim.x);
  const int gsz = 8 * gy;
  const int group = wg / gsz;
  const int rem = wg - group * gsz;
  const int bm = (group * 8 + (rem & 7)) * 128;
  const int bn = (rem >> 3) * 128;

  f32x4 acc[4][4] = {};

  const int r0 = tid >> 2;
  const int c0 = (tid & 3) * 8;

  #pragma unroll
  for (int i = 0; i < 2; ++i) {
    int row = r0 + i * 64;
    gload16(&A[(size_t)(bm + row) * K + c0], &Alds[0][row * 32 + c0]);
    gload16(&Bt[(size_t)(bn + row) * K + c0], &Blds[0][row * 32 + c0]);
  }
  __syncthreads();

  int buf = 0;
  for (int k0 = 0; k0 < K; k0 += 32) {
    if (k0 + 32 < K) {
      #pragma unroll
      for (int i = 0; i < 2; ++i) {
        int row = r0 + i * 64;
        gload16(&A[(size_t)(bm + row) * K + k0 + 32 + c0], &Alds[buf ^ 1][row * 32 + c0]);
        gload16(&Bt[(size_t)(bn + row) * K + k0 + 32 + c0], &Blds[buf ^ 1][row * 32 + c0]);
      }
    }
    bf16x8 af[4], bf[4];
    #pragma unroll
    for (int m = 0; m < 4; ++m)
      af[m] = *(const bf16x8*)&Alds[buf][(wm * 64 + m * 16 + (lane & 15)) * 32 + (lane >> 4) * 8];
    #pragma unroll
    for (int n = 0; n < 4; ++n)
      bf[n] = *(const bf16x8*)&Blds[buf][(wn * 64 + n * 16 + (lane & 15)) * 32 + (lane >> 4) * 8];
    #pragma unroll
    for (int m = 0; m < 4; ++m)
      #pragma unroll
      for (int n = 0; n < 4; ++n)
        acc[m][n] = __builtin_amdgcn_mfma_f32_16x16x32_bf16(af[m], bf[n], acc[m][n], 0, 0, 0);
    __syncthreads();
    buf ^= 1;
  }

  const int crow0 = bm + wm * 64 + ((lane >> 4)) * 4;
  const int ccol0 = bn + wn * 64 + (lane & 15);
  #pragma unroll
  for (int m = 0; m < 4; ++m) {
    #pragma unroll
    for (int n = 0; n < 4; ++n) {
      int col = ccol0 + n * 16;
      #pragma unroll
      for (int r = 0; r < 4; ++r) {
        int row = crow0 + m * 16 + r;
        float v = acc[m][n][r];
        if constexpr (EPI & 1) v += bias[col];
        if constexpr (EPI & 4) v += resid[(size_t)row * N + col];
        if constexpr (EPI & 2) v = fmaxf(v, 0.f);
        if constexpr (EPI & 8) Cf[(size_t)row * N + col] = v;
        if constexpr (EPI & 16) Cb[(size_t)row * N + col] = f2bf(v);
      }
    }
  }
}

// --------------------------------------------------------- GEMM 256x256 ---
// 8-phase, 8 waves (2M x 4N), BK=64, 128 KB LDS dbuf, T2 swizzle.
// v3 ledger (stage -> first read >= 4 phases; wait covers loads >= 3 phases
// old; region death verified):
//   Ph1: stage (t+1).AQ1   Ph2: (t+1).AQ2 + vmcnt(8)
//   Ph3: (t+2).BL          Ph4: (t+2).BH  + vmcnt(6)
//   Ph5: (t+2).AQ1         Ph6: (t+2).AQ2 + vmcnt(8)
//   Ph7: (t+3).BL          Ph8: (t+3).BH  + vmcnt(6)
// AQ1 = A rows {0-63, 128-191} (dead after Ph2); AQ2 = {64-127, 192-255}
// (dead after Ph4). B dead after Ph1/Ph5. nt must be even, >= 4.
// MFMA order: k-half outermost (dependency distance 8).

#define STGB(b, h, kt) {                                                   \
    _Pragma("unroll") for (int _l = 0; _l < 2; ++_l) {                     \
      int _r = (h) * 128 + _l * 64 + s_row;                                \
      gload16(&Bt[(size_t)(bn + _r) * K + kof + (kt) * 64 + s_gc8],        \
              &lds[b][1][_r * 64 + s_sc8]);                                \
    } }

#define STGA(b, qd, kt) {                                                  \
    _Pragma("unroll") for (int _l = 0; _l < 2; ++_l) {                     \
      int _r = (qd) * 64 + _l * 128 + s_row;                               \
      gload16(&A[(size_t)(bm + _r) * K + kof + (kt) * 64 + s_gc8],         \
              &lds[b][0][_r * 64 + s_sc8]);                                \
    } }

#define VMW(N) asm volatile("s_waitcnt vmcnt(" #N ")" ::: "memory")

#define PHASE(q, b, WITHB, STGSTMT, VMSTMT)                                 \
  {                                                                         \
    Af[0] = *(const bf16x8*)&lds[b][0][aBase + (2*(q)+0)*1024 + sc0];       \
    Af[1] = *(const bf16x8*)&lds[b][0][aBase + (2*(q)+0)*1024 + sc1];       \
    Af[2] = *(const bf16x8*)&lds[b][0][aBase + (2*(q)+1)*1024 + sc0];       \
    Af[3] = *(const bf16x8*)&lds[b][0][aBase + (2*(q)+1)*1024 + sc1];       \
    if (WITHB) {                                                            \
      _Pragma("unroll") for (int nf = 0; nf < 4; ++nf) {                    \
        Bf[nf*2+0] = *(const bf16x8*)&lds[b][1][bBase + nf*1024 + sc0];     \
        Bf[nf*2+1] = *(const bf16x8*)&lds[b][1][bBase + nf*1024 + sc1];     \
      }                                                                     \
    }                                                                       \
    STGSTMT;                                                                \
    __builtin_amdgcn_sched_barrier(0);                                      \
    __builtin_amdgcn_s_barrier();                                           \
    asm volatile("s_waitcnt lgkmcnt(0)" ::: "memory");                      \
    __builtin_amdgcn_sched_barrier(0);                                      \
    __builtin_amdgcn_s_setprio(1);                                          \
    _Pragma("unroll") for (int kk = 0; kk < 2; ++kk)                        \
      _Pragma("unroll") for (int mi = 0; mi < 2; ++mi)                      \
        _Pragma("unroll") for (int nf = 0; nf < 4; ++nf)                    \
          acc[2*(q)+mi][nf] = __builtin_amdgcn_mfma_f32_16x16x32_bf16(      \
              Af[mi*2+kk], Bf[nf*2+kk], acc[2*(q)+mi][nf], 0, 0, 0);        \
    __builtin_amdgcn_s_setprio(0);                                          \
    VMSTMT;                                                                 \
    __builtin_amdgcn_sched_barrier(0);                                      \
    __builtin_amdgcn_s_barrier();                                           \
  }

template <int EPI>
__global__ __launch_bounds__(512, 2)
void gemm256(const unsigned short* __restrict__ A,
             const unsigned short* __restrict__ Bt,
             const float* __restrict__ bias,
             const float* __restrict__ resid,
             float* __restrict__ Cf,
             unsigned short* __restrict__ Cb,
             int M, int N, int K, int gy, size_t segN) {
  __shared__ unsigned short lds[2][2][16384];   // [buf][A/B][256*64]
  const int tid = threadIdx.x;
  const int lane = tid & 63;
  const int w = tid >> 6;
  const int wr = w >> 2, wc = w & 3;            // 2 x 4 wave grid
  const int q16 = lane & 15, qt = lane >> 4;

  int wg = xcd_swz(blockIdx.x, gridDim.x);
  int ks = 0;
  if constexpr ((EPI & 64) != 0) { ks = wg & 1; wg >>= 1; }
  const int gsz = 4 * gy;                       // 4 bm-rows per XCD group
  const int group = wg / gsz;
  const int rem = wg - group * gsz;
  const int bm = (group * 4 + (rem & 3)) * 256;
  const int bn = (rem >> 2) * 256;

  const int Kh  = (EPI & 64) ? (K >> 1) : K;    // K per slice
  const int kof = ks * Kh;                      // column offset of this slice

  // staging map: dest row s_row(+offs), dest 16B chunk s_sc, swizzled src
  const int s_row = tid >> 3;                   // 0..63
  const int s_sc  = tid & 7;
  const int s_sc8 = s_sc * 8;
  const int s_gc8 = (s_sc ^ (s_row & 7)) * 8;

  // fragment read bases (elements); phys chunk = logical ^ (row&7)
  const int aBase = (wr * 128 + q16) * 64;
  const int bBase = (wc * 64 + q16) * 64;
  const int sc0 = (qt ^ (q16 & 7)) * 8;          // k-half 0
  const int sc1 = ((4 + qt) ^ (q16 & 7)) * 8;    // k-half 1

  f32x4 acc[8][4] = {};
  bf16x8 Af[4], Bf[8];

  const int nt = Kh >> 6;                       // even, >= 4

  // prologue: (0).BL,BH,AQ1,AQ2 + (1).BL,BH; vmcnt(6) leaves
  // [(0).AQ2, (1).BL, (1).BH] in flight = steady-state invariant.
  STGB(0, 0, 0) STGB(0, 1, 0) STGA(0, 0, 0) STGA(0, 1, 0)
  STGB(1, 0, 1) STGB(1, 1, 1)
  VMW(6);
  __builtin_amdgcn_s_barrier();

  #pragma unroll 1
  for (int t = 0; t < nt; t += 2) {
    const bool s2 = t + 2 < nt;                 // nt even -> s3 == s2
    // tile t in buf0
    PHASE(0, 0, true,  STGA(1, 0, t + 1),            (void)0)
    PHASE(1, 0, false, STGA(1, 1, t + 1),            VMW(8))
    PHASE(2, 0, false, if (s2) STGB(0, 0, t + 2),    (void)0)
    PHASE(3, 0, false, if (s2) STGB(0, 1, t + 2),    if (s2) { VMW(6); } else { VMW(2); })
    // tile t+1 in buf1
    PHASE(0, 1, true,  if (s2) STGA(0, 0, t + 2),    (void)0)
    PHASE(1, 1, false, if (s2) STGA(0, 1, t + 2),    if (s2) { VMW(8); } else { VMW(0); })
    PHASE(2, 1, false, if (s2) STGB(1, 0, t + 3),    (void)0)
    PHASE(3, 1, false, if (s2) STGB(1, 1, t + 3),    if (s2) { VMW(6); } else { VMW(0); })
  }

  // epilogue
  const int crow0 = bm + wr * 128 + qt * 4;
  const int ccol0 = bn + wc * 64 + q16;
  const int seg = bn / 768;
  const int lcol0 = (bn % 768) + wc * 64 + q16;
  #pragma unroll
  for (int mf = 0; mf < 8; ++mf) {
    #pragma unroll
    for (int nf = 0; nf < 4; ++nf) {
      int col = ccol0 + nf * 16;
      #pragma unroll
      for (int j = 0; j < 4; ++j) {
        int row = crow0 + mf * 16 + j;
        float v = acc[mf][nf][j];
        if constexpr (EPI & 64) {
          if (ks == 0) v += bias[col] + resid[(size_t)row * N + col];
          Cf[(size_t)ks * segN + (size_t)row * N + col] = v;
        } else {
          if constexpr (EPI & 1) v += bias[col];
          if constexpr (EPI & 4) v += resid[(size_t)row * N + col];
          if constexpr (EPI & 2) v = fmaxf(v, 0.f);
          if constexpr (EPI & 8) Cf[(size_t)row * N + col] = v;
          if constexpr (EPI & 16) Cb[(size_t)row * N + col] = f2bf(v);
          if constexpr (EPI & 32)
            Cb[(size_t)seg * segN + (size_t)row * 768 + lcol0 + nf * 16] = f2bf(v);
        }
      }
    }
  }
}

// ------------------------------------------------------------- attention ---
// Swapped-QK^T causal flash attention, paired q-blocks, static-max softmax.
__global__ void attn_fwd(const unsigned short* __restrict__ q,
                         const unsigned short* __restrict__ k,
                         const unsigned short* __restrict__ vT,
                         unsigned short* __restrict__ z) {
  __shared__ unsigned short Klds[2 * 2 * 64 * 32];
  __shared__ unsigned short Vlds[2 * 2 * 64 * 32];
  __shared__ unsigned short Plds[4 * 16 * 72];

  const int wgid = xcd_swz(blockIdx.x, gridDim.x);
  const int pi = wgid & 15;
  const int bh = wgid >> 4;
  const int b = bh / 12, h = bh % 12;
  const int tid = threadIdx.x, lane = tid & 63, w = tid >> 6;
  const int q16 = lane & 15;
  const int qt  = lane >> 4;
  const int rdc = ((qt ^ ((q16 >> 1) & 3)) * 8);

  const int srow = tid >> 2;
  const int sdc  = (tid & 3) * 8;
  const int sgc  = (((tid & 3) ^ ((srow >> 1) & 3)) * 8);
  const size_t kbase = (size_t)(b * 2048) * 768 + h * 64;
  const size_t vbase = (size_t)((b * 12 + h) * 64) * 2048;
  unsigned short* Pw = &Plds[w * 16 * 72];

  #pragma unroll 1
  for (int seg = 0; seg < 2; ++seg) {
    const int qb = seg == 0 ? pi : 31 - pi;
    const int q0 = qb * 64;
    const int nt = qb + 1;

    const int qrow = q0 + w * 16 + q16;
    const size_t qoff = (size_t)(b * 2048 + qrow) * 768 + h * 64 + qt * 8;
    bf16x8 qf0 = *(const bf16x8*)&q[qoff];
    bf16x8 qf1 = *(const bf16x8*)&q[qoff + 32];

    f32x4 accO[4] = {};
    float lrow = 0.f;

    #pragma unroll
    for (int i = 0; i < 2; ++i) {
      gload16(&k[kbase + (size_t)srow * 768 + i * 32 + sgc],
              &Klds[i * 2048 + srow * 32 + sdc]);
      gload16(&vT[vbase + (size_t)srow * 2048 + i * 32 + sgc],
              &Vlds[i * 2048 + srow * 32 + sdc]);
    }
    __syncthreads();

    int buf = 0;
    for (int t = 0; t < nt; ++t) {
      if (t + 1 < nt) {
        const int kv1 = (t + 1) * 64;
        const int bo = (buf ^ 1) * 4096;
        #pragma unroll
        for (int i = 0; i < 2; ++i) {
          gload16(&k[kbase + (size_t)(kv1 + srow) * 768 + i * 32 + sgc],
                  &Klds[bo + i * 2048 + srow * 32 + sdc]);
          gload16(&vT[vbase + (size_t)srow * 2048 + kv1 + i * 32 + sgc],
                  &Vlds[bo + i * 2048 + srow * 32 + sdc]);
        }
      }

      const int kv0 = t * 64;
      const int kb_ = buf * 4096;

      // S = K Q^T: 4 independent k0-MFMAs, then 4 k1-MFMAs (dep distance 4)
      bf16x8 kf0[4], kf1[4];
      #pragma unroll
      for (int n = 0; n < 4; ++n) {
        kf0[n] = *(const bf16x8*)&Klds[kb_ + 0 * 2048 + (n * 16 + q16) * 32 + rdc];
        kf1[n] = *(const bf16x8*)&Klds[kb_ + 1 * 2048 + (n * 16 + q16) * 32 + rdc];
      }
      f32x4 s[4];
      __builtin_amdgcn_s_setprio(1);
      #pragma unroll
      for (int n = 0; n < 4; ++n) {
        f32x4 zz = {};
        s[n] = __builtin_amdgcn_mfma_f32_16x16x32_bf16(kf0[n], qf0, zz, 0, 0, 0);
      }
      #pragma unroll
      for (int n = 0; n < 4; ++n)
        s[n] = __builtin_amdgcn_mfma_f32_16x16x32_bf16(kf1[n], qf1, s[n], 0, 0, 0);
      __builtin_amdgcn_s_setprio(0);

      if (t == nt - 1) {
        const int rowg = q0 + w * 16 + q16;
        #pragma unroll
        for (int n = 0; n < 4; ++n)
          #pragma unroll
          for (int r = 0; r < 4; ++r)
            if (kv0 + n * 16 + qt * 4 + r > rowg) s[n][r] = -3.0e38f;
      }

      // p = exp2(s); in-lane partial row-sum (cross-lane sum deferred)
      #pragma unroll
      for (int n = 0; n < 4; ++n)
        #pragma unroll
        for (int r = 0; r < 4; ++r) { s[n][r] = exp2f(s[n][r]); lrow += s[n][r]; }

      #pragma unroll
      for (int n = 0; n < 4; ++n) {
        unsigned int lo, hi;
        asm("v_cvt_pk_bf16_f32 %0, %1, %2" : "=v"(lo) : "v"(s[n][0]), "v"(s[n][1]));
        asm("v_cvt_pk_bf16_f32 %0, %1, %2" : "=v"(hi) : "v"(s[n][2]), "v"(s[n][3]));
        uint2 pk; pk.x = lo; pk.y = hi;
        *(uint2*)&Pw[q16 * 72 + n * 16 + qt * 4] = pk;
      }

      __builtin_amdgcn_s_setprio(1);
      #pragma unroll
      for (int kk = 0; kk < 2; ++kk) {
        bf16x8 pf = *(const bf16x8*)&Pw[q16 * 72 + kk * 32 + qt * 8];
        #pragma unroll
        for (int n = 0; n < 4; ++n) {
          bf16x8 vf = *(const bf16x8*)&Vlds[kb_ + kk * 2048 + (n * 16 + q16) * 32 + rdc];
          accO[n] = __builtin_amdgcn_mfma_f32_16x16x32_bf16(pf, vf, accO[n], 0, 0, 0);
        }
      }
      __builtin_amdgcn_s_setprio(0);

      __syncthreads();
      buf ^= 1;
    }

    // epilogue: complete the row sum across kv-quarter lanes, then divide
    lrow += __shfl_xor(lrow, 16);
    lrow += __shfl_xor(lrow, 32);
    #pragma unroll
    for (int r = 0; r < 4; ++r) {
      float lr = __int_as_float(__builtin_amdgcn_ds_bpermute((qt * 4 + r) * 4,
                                                             __float_as_int(lrow)));
      float linv = 1.0f / lr;
      int rowg = q0 + w * 16 + qt * 4 + r;
      #pragma unroll
      for (int n = 0; n < 4; ++n)
        z[(size_t)(b * 2048 + rowg) * 768 + h * 64 + n * 16 + q16]
            = f2bf(accO[n][r] * linv);
    }
  }
}

// ---------------------------------------------------------------- launch ---
extern "C" void kernel_launch(void* const* d_in, const int* in_sizes, int n_in,
                              void* d_out, int out_size, void* d_ws, size_t ws_size,
                              hipStream_t stream) {
  const float* x  = (const float*)d_in[0];
  const float* Wq = (const float*)d_in[1];
  const float* Wk = (const float*)d_in[2];
  const float* Wv = (const float*)d_in[3];
  const float* Wo = (const float*)d_in[4];
  const float* bo = (const float*)d_in[5];
  const float* W1 = (const float*)d_in[6];
  const float* b1 = (const float*)d_in[7];
  const float* W2 = (const float*)d_in[8];
  const float* b2 = (const float*)d_in[9];
  float* out = (float*)d_out;

  const int B = 4, S = 2048, D = 768, H = 12, hs = 64, F = 3072;
  const int M = B * S;                 // 8192
  const size_t MD = (size_t)M * D;     // 6291456

  unsigned short* xb   = (unsigned short*)d_ws;
  unsigned short* qb   = xb + MD;
  unsigned short* kb   = qb + MD;
  unsigned short* vb   = kb + MD;
  unsigned short* hbuf = xb;           // [M, F] bf16, reuse
  unsigned short* vT   = vb + MD;
  unsigned short* zb   = vT + MD;
  float*          z2f  = (float*)(zb + MD);
  unsigned short* z2b  = (unsigned short*)(z2f + MD);
  unsigned short* wqkvT= z2b + MD;     // [2304][768] bf16
  unsigned short* woT  = wqkvT + 3 * (size_t)D * D;
  unsigned short* w1T  = woT + (size_t)D * D;
  unsigned short* w2T  = w1T + (size_t)D * F;
  // W2 split-K partials: 2 x MD fp32 = qb..vT region (dead after attn)
  float*          part = (float*)qb;

  dim3 tb(32, 8);

  castx<<<dim3((int)(MD / 4 / 256)), 256, 0, stream>>>(x, xb, (int)MD);

  // q scale folds 1/sqrt(64) AND log2(e): softmax runs in exp2 domain
  const float QS = 0.125f * 1.4426950408889634f;
  tcast3<<<dim3(hs / 32, D / 32, 3 * H), tb, 0, stream>>>(Wq, Wk, Wv, wqkvT, QS);
  tcast<<<dim3(D / 32, D / 32, 1), tb, 0, stream>>>(Wo, woT, D, D, 1.0f);
  tcast<<<dim3(F / 32, D / 32, 1), tb, 0, stream>>>(W1, w1T, D, F, 1.0f);
  tcast<<<dim3(D / 32, F / 32, 1), tb, 0, stream>>>(W2, w2T, F, D, 1.0f);

  // fused QKV: [M,768] @ [768,2304] -> q,k,v bf16 (split store), 256² 8-phase
  {
    int gy = 3 * D / 256;  // 9
    gemm256<32><<<dim3((M / 256) * gy), 512, 0, stream>>>(xb, wqkvT, nullptr, nullptr,
                                                          nullptr, qb, M, 3 * D, D, gy, MD);
  }

  vtrans<<<dim3(S / 32, hs / 32, B * H), tb, 0, stream>>>(vb, vT);

  attn_fwd<<<dim3((S / 128) * B * H), 256, 0, stream>>>(qb, kb, vT, zb);

  // z @ Wo + bo + x -> z2 (fp32 + bf16), 128² kernel
  {
    int gy = D / 128;  // 6
    gemm_bf16<1 | 4 | 8 | 16><<<dim3(64 * gy), 256, 0, stream>>>(zb, woT, bo, x,
                                                                 z2f, z2b, M, D, D, gy, 0);
  }
  // relu(z2 @ W1 + b1) -> h (bf16), 256² 8-phase
  {
    int gy = F / 256;  // 12
    gemm256<1 | 2 | 16><<<dim3((M / 256) * gy), 512, 0, stream>>>(z2b, w1T, b1, nullptr,
                                                                  nullptr, hbuf, M, F, D, gy, 0);
  }
  // h @ W2: split-K=2 partials (slice0 folds b2 + z2f resid), then reduce
  {
    int gy = D / 256;  // 3
    gemm256<64><<<dim3(2 * (M / 256) * gy), 512, 0, stream>>>(hbuf, w2T, b2, z2f,
                                                              part, nullptr, M, D, F, gy, MD);
    reduce2<<<dim3((int)(MD / 4 / 256)), 256, 0, stream>>>(part, out, (int)MD);
  }
}

// Round 9
// 273.124 us; speedup vs baseline: 1.1104x; 1.1104x over previous
//
#include <hip/hip_runtime.h>

// ---------------------------------------------------------------------------
// TransformerBlock on MI355X (gfx950): bf16 MFMA pipeline
//   B=4 S=2048 D=768 H=12 hs=64 F=3072, M=B*S=8192
// Round 9: counted-vmcnt barrier scheme (stage(t+1) -> vmcnt(4) -> raw
//          s_barrier -> compute -> raw s_barrier) in BOTH the 128x128 GEMM
//          and attention — removes the per-step vmcnt(0) drain that made
//          every K-step cost a full memory latency. All GEMMs on 128² with
//          large grids. Static-max softmax attention retained.
// ---------------------------------------------------------------------------

typedef __attribute__((ext_vector_type(4))) float f32x4;
typedef __attribute__((ext_vector_type(8))) short bf16x8;   // 8 bf16 in 4 VGPRs
typedef __attribute__((ext_vector_type(4))) unsigned short u16x4;

#define GLB_AS __attribute__((address_space(1)))
#define LDS_AS __attribute__((address_space(3)))

__device__ __forceinline__ unsigned short f2bf(float f) {
  unsigned int u = __float_as_uint(f);
  u = (u + 0x7FFFu + ((u >> 16) & 1u)) >> 16;   // RNE
  return (unsigned short)u;
}

__device__ __forceinline__ void gload16(const void* g, void* l) {
  __builtin_amdgcn_global_load_lds((const GLB_AS unsigned int*)g,
                                   (LDS_AS unsigned int*)l, 16, 0, 0);
}

// bijective XCD swizzle (m204): contiguous chunk of wg-ids per XCD
__device__ __forceinline__ int xcd_swz(int orig, int nwg) {
  int q = nwg >> 3, r = nwg & 7;
  int xcd = orig & 7, rest = orig >> 3;
  return (xcd < r ? xcd * (q + 1) : r * (q + 1) + (xcd - r) * q) + rest;
}

#define VMW4 asm volatile("s_waitcnt vmcnt(4)" ::: "memory")
#define VMW0 asm volatile("s_waitcnt vmcnt(0)" ::: "memory")

// ---------------------------------------------------------------- cast x ---
__global__ void castx(const float* __restrict__ in, unsigned short* __restrict__ out, int n) {
  int i = (blockIdx.x * 256 + threadIdx.x) * 4;
  if (i < n) {
    float4 f = *(const float4*)&in[i];
    u16x4 o;
    o[0] = f2bf(f.x); o[1] = f2bf(f.y); o[2] = f2bf(f.z); o[3] = f2bf(f.w);
    *(u16x4*)&out[i] = o;
  }
}

// ---------------------------------------------- weight transpose + cast ----
__global__ void tcast(const float* __restrict__ in, unsigned short* __restrict__ out,
                      int R, int C, float scale) {
  __shared__ float tile[32][33];
  const float* inb = in + (size_t)blockIdx.z * R * C;
  unsigned short* outb = out + (size_t)blockIdx.z * R * C;
  int bx = blockIdx.x * 32;  // C dim
  int by = blockIdx.y * 32;  // R dim
  int tx = threadIdx.x, ty = threadIdx.y;
  #pragma unroll
  for (int i = 0; i < 32; i += 8)
    tile[ty + i][tx] = inb[(size_t)(by + ty + i) * C + bx + tx];
  __syncthreads();
  #pragma unroll
  for (int i = 0; i < 32; i += 8)
    outb[(size_t)(bx + ty + i) * R + by + tx] = f2bf(tile[tx][ty + i] * scale);
}

// Wq/Wk/Wv transposes in one launch: z in [0,36), wsel=z/12 picks the matrix.
__global__ void tcast3(const float* __restrict__ Wq, const float* __restrict__ Wk,
                       const float* __restrict__ Wv, unsigned short* __restrict__ out,
                       float qscale) {
  __shared__ float tile[32][33];
  const int R = 768, C = 64;
  int z = blockIdx.z, wsel = z / 12, head = z % 12;
  const float* in = (wsel == 0 ? Wq : wsel == 1 ? Wk : Wv) + (size_t)head * R * C;
  unsigned short* outb = out + (size_t)wsel * R * R + (size_t)head * R * C;
  float scale = wsel == 0 ? qscale : 1.0f;
  int bx = blockIdx.x * 32;  // C dim
  int by = blockIdx.y * 32;  // R dim
  int tx = threadIdx.x, ty = threadIdx.y;
  #pragma unroll
  for (int i = 0; i < 32; i += 8)
    tile[ty + i][tx] = in[(size_t)(by + ty + i) * C + bx + tx];
  __syncthreads();
  #pragma unroll
  for (int i = 0; i < 32; i += 8)
    outb[(size_t)(bx + ty + i) * R + by + tx] = f2bf(tile[tx][ty + i] * scale);
}

// ------------------------------------------------- v -> vT (bf16->bf16) ----
__global__ void vtrans(const unsigned short* __restrict__ v, unsigned short* __restrict__ vT) {
  __shared__ unsigned short tile[32][33];
  int bh = blockIdx.z, b = bh / 12, h = bh % 12;
  int s0 = blockIdx.x * 32, e0 = blockIdx.y * 32;
  int tx = threadIdx.x, ty = threadIdx.y;
  #pragma unroll
  for (int i = 0; i < 32; i += 8)
    tile[ty + i][tx] = v[(size_t)(b * 2048 + s0 + ty + i) * 768 + h * 64 + e0 + tx];
  __syncthreads();
  #pragma unroll
  for (int i = 0; i < 32; i += 8)
    vT[(size_t)((b * 12 + h) * 64 + e0 + ty + i) * 2048 + s0 + tx] = tile[tx][ty + i];
}

// --------------------------------------------------------- GEMM 128x128 ---
// C[M,N] = A[M,K] @ Bt[N,K]^T ; EPI bits: 1 bias, 2 relu, 4 resid(fp32),
// 8 fp32 store, 16 bf16 store, 32 QKV split bf16 store.
// K-loop: double-buffered LDS; stage(t+1) issued, then vmcnt(4) (waits only
// stage(t), issued a full K-step earlier), raw s_barrier, ds_read+MFMA with
// compiler-managed lgkm waits, raw s_barrier. No full vmcnt drain in loop.
template <int EPI>
__global__ void gemm_bf16(const unsigned short* __restrict__ A,
                          const unsigned short* __restrict__ Bt,
                          const float* __restrict__ bias,
                          const float* __restrict__ resid,
                          float* __restrict__ Cf,
                          unsigned short* __restrict__ Cb,
                          int M, int N, int K, int gy, size_t segN) {
  __shared__ unsigned short Alds[2][128 * 32];
  __shared__ unsigned short Blds[2][128 * 32];
  const int tid = threadIdx.x;
  const int lane = tid & 63;
  const int w = tid >> 6;
  const int wm = w & 1, wn = w >> 1;
  const int wg = xcd_swz(blockIdx.x, gridDim.x);
  const int gsz = 8 * gy;
  const int group = wg / gsz;
  const int rem = wg - group * gsz;
  const int bm = (group * 8 + (rem & 7)) * 128;
  const int bn = (rem >> 3) * 128;

  f32x4 acc[4][4] = {};

  const int r0 = tid >> 2;
  const int c0 = (tid & 3) * 8;

  // prologue: stage tile 0 into buf 0; full drain once
  #pragma unroll
  for (int i = 0; i < 2; ++i) {
    int row = r0 + i * 64;
    gload16(&A[(size_t)(bm + row) * K + c0], &Alds[0][row * 32 + c0]);
    gload16(&Bt[(size_t)(bn + row) * K + c0], &Blds[0][row * 32 + c0]);
  }
  __syncthreads();

  int buf = 0;
  for (int k0 = 0; k0 < K; k0 += 32) {
    if (k0 + 32 < K) {
      #pragma unroll
      for (int i = 0; i < 2; ++i) {
        int row = r0 + i * 64;
        gload16(&A[(size_t)(bm + row) * K + k0 + 32 + c0], &Alds[buf ^ 1][row * 32 + c0]);
        gload16(&Bt[(size_t)(bn + row) * K + k0 + 32 + c0], &Blds[buf ^ 1][row * 32 + c0]);
      }
      VMW4;      // waits only the 4 loads of tile t (one K-step old)
    } else {
      VMW0;      // tail: current tile's stage must be complete
    }
    __builtin_amdgcn_s_barrier();    // all waves confirmed stage(t) landed

    bf16x8 af[4], bf[4];
    #pragma unroll
    for (int m = 0; m < 4; ++m)
      af[m] = *(const bf16x8*)&Alds[buf][(wm * 64 + m * 16 + (lane & 15)) * 32 + (lane >> 4) * 8];
    #pragma unroll
    for (int n = 0; n < 4; ++n)
      bf[n] = *(const bf16x8*)&Blds[buf][(wn * 64 + n * 16 + (lane & 15)) * 32 + (lane >> 4) * 8];
    #pragma unroll
    for (int m = 0; m < 4; ++m)
      #pragma unroll
      for (int n = 0; n < 4; ++n)
        acc[m][n] = __builtin_amdgcn_mfma_f32_16x16x32_bf16(af[m], bf[n], acc[m][n], 0, 0, 0);

    __builtin_amdgcn_s_barrier();    // reads(t) consumed before stage(t+2) overwrites
    buf ^= 1;
  }

  const int crow0 = bm + wm * 64 + ((lane >> 4)) * 4;
  const int ccol0 = bn + wn * 64 + (lane & 15);
  const int seg = bn / 768;                       // block-constant (768%128==0)
  const int lcol0 = (bn % 768) + wn * 64 + (lane & 15);
  #pragma unroll
  for (int m = 0; m < 4; ++m) {
    #pragma unroll
    for (int n = 0; n < 4; ++n) {
      int col = ccol0 + n * 16;
      #pragma unroll
      for (int r = 0; r < 4; ++r) {
        int row = crow0 + m * 16 + r;
        float v = acc[m][n][r];
        if constexpr (EPI & 1) v += bias[col];
        if constexpr (EPI & 4) v += resid[(size_t)row * N + col];
        if constexpr (EPI & 2) v = fmaxf(v, 0.f);
        if constexpr (EPI & 8) Cf[(size_t)row * N + col] = v;
        if constexpr (EPI & 16) Cb[(size_t)row * N + col] = f2bf(v);
        if constexpr (EPI & 32)
          Cb[(size_t)seg * segN + (size_t)row * 768 + lcol0 + n * 16] = f2bf(v);
      }
    }
  }
}

// ------------------------------------------------------------- attention ---
// Swapped-QK^T causal flash attention, paired q-blocks, static-max softmax,
// counted-vmcnt barriers (no per-tile vmcnt(0) drain).
__global__ void attn_fwd(const unsigned short* __restrict__ q,
                         const unsigned short* __restrict__ k,
                         const unsigned short* __restrict__ vT,
                         unsigned short* __restrict__ z) {
  __shared__ unsigned short Klds[2 * 2 * 64 * 32];
  __shared__ unsigned short Vlds[2 * 2 * 64 * 32];
  __shared__ unsigned short Plds[4 * 16 * 72];

  const int wgid = xcd_swz(blockIdx.x, gridDim.x);
  const int pi = wgid & 15;
  const int bh = wgid >> 4;
  const int b = bh / 12, h = bh % 12;
  const int tid = threadIdx.x, lane = tid & 63, w = tid >> 6;
  const int q16 = lane & 15;
  const int qt  = lane >> 4;
  const int rdc = ((qt ^ ((q16 >> 1) & 3)) * 8);

  const int srow = tid >> 2;
  const int sdc  = (tid & 3) * 8;
  const int sgc  = (((tid & 3) ^ ((srow >> 1) & 3)) * 8);
  const size_t kbase = (size_t)(b * 2048) * 768 + h * 64;
  const size_t vbase = (size_t)((b * 12 + h) * 64) * 2048;
  unsigned short* Pw = &Plds[w * 16 * 72];

  #pragma unroll 1
  for (int seg = 0; seg < 2; ++seg) {
    const int qb = seg == 0 ? pi : 31 - pi;
    const int q0 = qb * 64;
    const int nt = qb + 1;

    const int qrow = q0 + w * 16 + q16;
    const size_t qoff = (size_t)(b * 2048 + qrow) * 768 + h * 64 + qt * 8;
    bf16x8 qf0 = *(const bf16x8*)&q[qoff];
    bf16x8 qf1 = *(const bf16x8*)&q[qoff + 32];

    f32x4 accO[4] = {};
    float lrow = 0.f;

    #pragma unroll
    for (int i = 0; i < 2; ++i) {
      gload16(&k[kbase + (size_t)srow * 768 + i * 32 + sgc],
              &Klds[i * 2048 + srow * 32 + sdc]);
      gload16(&vT[vbase + (size_t)srow * 2048 + i * 32 + sgc],
              &Vlds[i * 2048 + srow * 32 + sdc]);
    }
    __syncthreads();     // full drain once per segment

    int buf = 0;
    for (int t = 0; t < nt; ++t) {
      if (t + 1 < nt) {
        const int kv1 = (t + 1) * 64;
        const int bo = (buf ^ 1) * 4096;
        #pragma unroll
        for (int i = 0; i < 2; ++i) {
          gload16(&k[kbase + (size_t)(kv1 + srow) * 768 + i * 32 + sgc],
                  &Klds[bo + i * 2048 + srow * 32 + sdc]);
          gload16(&vT[vbase + (size_t)srow * 2048 + kv1 + i * 32 + sgc],
                  &Vlds[bo + i * 2048 + srow * 32 + sdc]);
        }
        VMW4;            // waits only stage(t) (issued last iteration)
      } else {
        VMW0;
      }
      __builtin_amdgcn_s_barrier();   // stage(t) visible to all waves

      const int kv0 = t * 64;
      const int kb_ = buf * 4096;

      // S = K Q^T: 4 independent k0-MFMAs, then 4 k1-MFMAs
      bf16x8 kf0[4], kf1[4];
      #pragma unroll
      for (int n = 0; n < 4; ++n) {
        kf0[n] = *(const bf16x8*)&Klds[kb_ + 0 * 2048 + (n * 16 + q16) * 32 + rdc];
        kf1[n] = *(const bf16x8*)&Klds[kb_ + 1 * 2048 + (n * 16 + q16) * 32 + rdc];
      }
      f32x4 s[4];
      __builtin_amdgcn_s_setprio(1);
      #pragma unroll
      for (int n = 0; n < 4; ++n) {
        f32x4 zz = {};
        s[n] = __builtin_amdgcn_mfma_f32_16x16x32_bf16(kf0[n], qf0, zz, 0, 0, 0);
      }
      #pragma unroll
      for (int n = 0; n < 4; ++n)
        s[n] = __builtin_amdgcn_mfma_f32_16x16x32_bf16(kf1[n], qf1, s[n], 0, 0, 0);
      __builtin_amdgcn_s_setprio(0);

      if (t == nt - 1) {
        const int rowg = q0 + w * 16 + q16;
        #pragma unroll
        for (int n = 0; n < 4; ++n)
          #pragma unroll
          for (int r = 0; r < 4; ++r)
            if (kv0 + n * 16 + qt * 4 + r > rowg) s[n][r] = -3.0e38f;
      }

      // p = exp2(s); in-lane partial row-sum (cross-lane sum deferred)
      #pragma unroll
      for (int n = 0; n < 4; ++n)
        #pragma unroll
        for (int r = 0; r < 4; ++r) { s[n][r] = exp2f(s[n][r]); lrow += s[n][r]; }

      #pragma unroll
      for (int n = 0; n < 4; ++n) {
        unsigned int lo, hi;
        asm("v_cvt_pk_bf16_f32 %0, %1, %2" : "=v"(lo) : "v"(s[n][0]), "v"(s[n][1]));
        asm("v_cvt_pk_bf16_f32 %0, %1, %2" : "=v"(hi) : "v"(s[n][2]), "v"(s[n][3]));
        uint2 pk; pk.x = lo; pk.y = hi;
        *(uint2*)&Pw[q16 * 72 + n * 16 + qt * 4] = pk;
      }

      __builtin_amdgcn_s_setprio(1);
      #pragma unroll
      for (int kk = 0; kk < 2; ++kk) {
        bf16x8 pf = *(const bf16x8*)&Pw[q16 * 72 + kk * 32 + qt * 8];
        #pragma unroll
        for (int n = 0; n < 4; ++n) {
          bf16x8 vf = *(const bf16x8*)&Vlds[kb_ + kk * 2048 + (n * 16 + q16) * 32 + rdc];
          accO[n] = __builtin_amdgcn_mfma_f32_16x16x32_bf16(pf, vf, accO[n], 0, 0, 0);
        }
      }
      __builtin_amdgcn_s_setprio(0);

      __builtin_amdgcn_s_barrier();   // reads(t) consumed before stage(t+2) overwrites
      buf ^= 1;
    }

    // epilogue: complete the row sum across kv-quarter lanes, then divide
    lrow += __shfl_xor(lrow, 16);
    lrow += __shfl_xor(lrow, 32);
    #pragma unroll
    for (int r = 0; r < 4; ++r) {
      float lr = __int_as_float(__builtin_amdgcn_ds_bpermute((qt * 4 + r) * 4,
                                                             __float_as_int(lrow)));
      float linv = 1.0f / lr;
      int rowg = q0 + w * 16 + qt * 4 + r;
      #pragma unroll
      for (int n = 0; n < 4; ++n)
        z[(size_t)(b * 2048 + rowg) * 768 + h * 64 + n * 16 + q16]
            = f2bf(accO[n][r] * linv);
    }
  }
}

// ---------------------------------------------------------------- launch ---
extern "C" void kernel_launch(void* const* d_in, const int* in_sizes, int n_in,
                              void* d_out, int out_size, void* d_ws, size_t ws_size,
                              hipStream_t stream) {
  const float* x  = (const float*)d_in[0];
  const float* Wq = (const float*)d_in[1];
  const float* Wk = (const float*)d_in[2];
  const float* Wv = (const float*)d_in[3];
  const float* Wo = (const float*)d_in[4];
  const float* bo = (const float*)d_in[5];
  const float* W1 = (const float*)d_in[6];
  const float* b1 = (const float*)d_in[7];
  const float* W2 = (const float*)d_in[8];
  const float* b2 = (const float*)d_in[9];
  float* out = (float*)d_out;

  const int B = 4, S = 2048, D = 768, H = 12, hs = 64, F = 3072;
  const int M = B * S;                 // 8192
  const size_t MD = (size_t)M * D;     // 6291456

  unsigned short* xb   = (unsigned short*)d_ws;
  unsigned short* qb   = xb + MD;
  unsigned short* kb   = qb + MD;
  unsigned short* vb   = kb + MD;
  unsigned short* hbuf = xb;           // [M, F] bf16, reuse
  unsigned short* vT   = vb + MD;
  unsigned short* zb   = vT + MD;
  float*          z2f  = (float*)(zb + MD);
  unsigned short* z2b  = (unsigned short*)(z2f + MD);
  unsigned short* wqkvT= z2b + MD;     // [2304][768] bf16
  unsigned short* woT  = wqkvT + 3 * (size_t)D * D;
  unsigned short* w1T  = woT + (size_t)D * D;
  unsigned short* w2T  = w1T + (size_t)D * F;

  dim3 tb(32, 8);

  castx<<<dim3((int)(MD / 4 / 256)), 256, 0, stream>>>(x, xb, (int)MD);

  // q scale folds 1/sqrt(64) AND log2(e): softmax runs in exp2 domain
  const float QS = 0.125f * 1.4426950408889634f;
  tcast3<<<dim3(hs / 32, D / 32, 3 * H), tb, 0, stream>>>(Wq, Wk, Wv, wqkvT, QS);
  tcast<<<dim3(D / 32, D / 32, 1), tb, 0, stream>>>(Wo, woT, D, D, 1.0f);
  tcast<<<dim3(F / 32, D / 32, 1), tb, 0, stream>>>(W1, w1T, D, F, 1.0f);
  tcast<<<dim3(D / 32, F / 32, 1), tb, 0, stream>>>(W2, w2T, F, D, 1.0f);

  // fused QKV: [M,768] @ [768,2304] -> q,k,v bf16 (split store), 1152 blocks
  {
    int gy = 3 * D / 128;  // 18
    gemm_bf16<32><<<dim3(64 * gy), 256, 0, stream>>>(xb, wqkvT, nullptr, nullptr,
                                                     nullptr, qb, M, 3 * D, D, gy, MD);
  }

  vtrans<<<dim3(S / 32, hs / 32, B * H), tb, 0, stream>>>(vb, vT);

  attn_fwd<<<dim3((S / 128) * B * H), 256, 0, stream>>>(qb, kb, vT, zb);

  // z @ Wo + bo + x -> z2 (fp32 + bf16)
  {
    int gy = D / 128;  // 6
    gemm_bf16<1 | 4 | 8 | 16><<<dim3(64 * gy), 256, 0, stream>>>(zb, woT, bo, x,
                                                                 z2f, z2b, M, D, D, gy, 0);
  }
  // relu(z2 @ W1 + b1) -> h (bf16), 1536 blocks
  {
    int gy = F / 128;  // 24
    gemm_bf16<1 | 2 | 16><<<dim3(64 * gy), 256, 0, stream>>>(z2b, w1T, b1, nullptr,
                                                             nullptr, hbuf, M, F, D, gy, 0);
  }
  // h @ W2 + b2 + z2 -> out (fp32)
  {
    int gy = D / 128;  // 6
    gemm_bf16<1 | 4 | 8><<<dim3(64 * gy), 256, 0, stream>>>(hbuf, w2T, b2, z2f,
                                                            out, nullptr, M, D, F, gy, 0);
  }
}